// Round 6
// baseline (700.825 us; speedup 1.0000x reference)
//
#include <hip/hip_runtime.h>
#include <hip/hip_bf16.h>

typedef unsigned short u16;
typedef __attribute__((ext_vector_type(8))) short short8;
typedef __attribute__((ext_vector_type(4))) float f32x4;
typedef __attribute__((ext_vector_type(4))) unsigned short us4;
typedef __attribute__((ext_vector_type(8))) unsigned short us8;

__device__ __forceinline__ u16 f2bf(float f) {
  unsigned int u = __float_as_uint(f);
  u += 0x7fffu + ((u >> 16) & 1u);
  return (u16)(u >> 16);
}
__device__ __forceinline__ float bf2f(u16 h) {
  return __uint_as_float(((unsigned int)h) << 16);
}
// gelu1p(x) = 1 + x * Phi(x); Phi via A&S 7.1.26 erf approx (|eps|<=1.5e-7).
__device__ __forceinline__ float gelu1p_f(float x) {
  const float z  = x * 0.7071067811865475f;
  const float az = __builtin_fabsf(z);
  const float t  = __builtin_amdgcn_rcpf(__builtin_fmaf(0.3275911f, az, 1.0f));
  float pl = __builtin_fmaf(1.061405429f, t, -1.453152027f);
  pl = __builtin_fmaf(pl, t, 1.421413741f);
  pl = __builtin_fmaf(pl, t, -0.284496736f);
  pl = __builtin_fmaf(pl, t, 0.254829592f);
  pl = pl * t;
  const float e = __builtin_amdgcn_exp2f(-az * az * 1.4426950408889634f);
  float erfa = __builtin_fmaf(-pl, e, 1.0f);
  erfa = __builtin_copysignf(erfa, z);
  return __builtin_fmaf(x, 0.5f * (1.0f + erfa), 1.0f);
}
__device__ __forceinline__ void gll16(const void* g, void* l) {
  __builtin_amdgcn_global_load_lds(
      (const __attribute__((address_space(1))) unsigned int*)g,
      (__attribute__((address_space(3))) unsigned int*)l, 16, 0, 0);
}
#define FENCE() __builtin_amdgcn_sched_barrier(0)
#define BARRIER() __builtin_amdgcn_s_barrier()
#define LGKM0() do { asm volatile("s_waitcnt lgkmcnt(0)" ::: "memory"); FENCE(); } while (0)
#define VMCNT4() do { asm volatile("s_waitcnt vmcnt(4)" ::: "memory"); FENCE(); } while (0)
#define VMCNT0() do { asm volatile("s_waitcnt vmcnt(0)" ::: "memory"); FENCE(); } while (0)
#define MFMA16(a, b, c) __builtin_amdgcn_mfma_f32_16x16x32_bf16(a, b, c, 0, 0, 0)

// ---------------------------------------------------------------------------
// Kernel 1: effective weights  W_eff = W + up[i] @ down[i]   (bf16 out)
// ---------------------------------------------------------------------------
__global__ __launch_bounds__(256)
void build_weff(const float* __restrict__ wq, const float* __restrict__ wk,
                const float* __restrict__ wv, const float* __restrict__ wo,
                const float* __restrict__ lqd, const float* __restrict__ lqu,
                const float* __restrict__ lkd, const float* __restrict__ lku,
                const float* __restrict__ lvd, const float* __restrict__ lvu,
                const float* __restrict__ lod, const float* __restrict__ lou,
                const int* __restrict__ idxp,
                u16* __restrict__ wqkv, u16* __restrict__ wout) {
  const int blk = blockIdx.x;        // 0..4095
  const int p = blk >> 10;
  const int n = blk & 1023;
  const int i = *idxp;
  const float* W  = (p == 0) ? wq  : (p == 1) ? wk  : (p == 2) ? wv  : wo;
  const float* Dn = ((p == 0) ? lqd : (p == 1) ? lkd : (p == 2) ? lvd : lod) + (size_t)i * 16 * 1024;
  const float* Up = ((p == 0) ? lqu : (p == 1) ? lku : (p == 2) ? lvu : lou) + (size_t)i * 1024 * 16;

  float up[16];
#pragma unroll
  for (int r = 0; r < 16; ++r) up[r] = Up[n * 16 + r];

  const int k0 = threadIdx.x << 2;
  f32x4 acc = *(const f32x4*)&W[(size_t)n * 1024 + k0];
#pragma unroll
  for (int r = 0; r < 16; ++r) {
    const f32x4 d = *(const f32x4*)&Dn[r * 1024 + k0];
#pragma unroll
    for (int j = 0; j < 4; ++j) acc[j] = __builtin_fmaf(up[r], d[j], acc[j]);
  }
  us4 o;
#pragma unroll
  for (int j = 0; j < 4; ++j) o[j] = f2bf(acc[j]);
  if (p < 3) *(us4*)&wqkv[(size_t)(p * 1024 + n) * 1024 + k0] = o;
  else       *(us4*)&wout[(size_t)n * 1024 + k0] = o;
}

// ---------------------------------------------------------------------------
// Kernel 2: x (f32) -> bf16
// ---------------------------------------------------------------------------
__global__ void xcast(const float* __restrict__ x, u16* __restrict__ xb) {
  const size_t i = ((size_t)blockIdx.x * 256 + threadIdx.x) * 8;
  f32x4 a = *(const f32x4*)(x + i);
  f32x4 b = *(const f32x4*)(x + i + 4);
  us8 o;
#pragma unroll
  for (int j = 0; j < 4; ++j) { o[j] = f2bf(a[j]); o[j + 4] = f2bf(b[j]); }
  *(us8*)(xb + i) = o;
}

// ---------------------------------------------------------------------------
// 128x128 4-wave 8-phase-style bf16 GEMM.  C[M,N] = A[M,1024] * B[N,1024]^T.
// BK=64, 4 waves (2Mx2N), per-wave 64x64 output, LDS 64 KiB -> 2 blocks/CU
// (the point: two INDEPENDENT workgroups per CU decorrelate barriers so the
// MFMA pipe stays fed while the other block drains reads/waits).
// LDS fragment-major per half (lane-linear b128 reads, linear gll_lds dest,
// 0 bank conflicts).  Per K-tile, 4 phases:
//   P0: read af[0-1],bf[0-1] (8); stage Ah1(t+1)->buf^1 ; MFMA m01xn01 (8)
//   P1: read af[2-3] (4);       stage Bh1(t+1)->buf^1 ; MFMA m23xn01 (8)
//   P2: read bf[2-3] (4);                               MFMA m23xn23 (8)
//   P3: no reads;  stage Ah0,Bh0(t+2)->buf ;            MFMA m01xn23 (8)
//   then vmcnt(4) (this-P3's 4 loads outstanding), barrier.
// Race-freedom: each staged region's last reader finished a barrier earlier
// (A-half read P0/P1; B-half0 read P0/P2 -> staged P3; cross-buf h1 staged
// P0/P1 into buf^1 whose readers finished last tile).  Tail clamps = dummy
// re-stages, drained by vmcnt(0) before epilogue.
// MODE 0: N=3072 fused qkv epilogue.  MODE 1: N=1024 f32 store.
// ---------------------------------------------------------------------------
template <int MODE>
__global__ __launch_bounds__(256, 2)
void gemm4w(const u16* __restrict__ A, const u16* __restrict__ Bw,
            u16* __restrict__ qb, u16* __restrict__ kbuf, u16* __restrict__ vbuf,
            float* __restrict__ outf, const int* __restrict__ mask, int nbx) {
  const int nwg = gridDim.x;
  const int cpx = nwg >> 3;                       // nwg % 8 == 0 (bijective)
  const int wg0 = blockIdx.x;
  const int swz = (wg0 & 7) * cpx + (wg0 >> 3);   // XCD-aware swizzle (T1)
  const int bx = swz % nbx;
  const int by = swz / nbx;
  const int row0 = by << 7, col0 = bx << 7;
  const int tid = threadIdx.x, lane = tid & 63, w = tid >> 6;
  const int wr = w >> 1, wc = w & 1;

  __shared__ __align__(16) u16 lds[2][2][2][4096];  // 64 KiB

  // per-thread pre-swizzled global offsets (fragment-major LDS):
  // sub = c*256+tid: mt=sub>>7, kk=(sub>>6)&1, kq=(sub>>4)&3, r=sub&15
  int goff[2];
#pragma unroll
  for (int c = 0; c < 2; ++c) {
    const int sub = c * 256 + tid;
    goff[c] = ((sub >> 7) * 16 + (sub & 15)) * 1024 + ((sub >> 6) & 1) * 32 + ((sub >> 4) & 3) * 8;
  }
  const u16* pA = A  + (size_t)row0 * 1024;
  const u16* pB = Bw + (size_t)col0 * 1024;

  auto stage = [&](int bb, int mat, int h, int ts) {
    const u16* base = (mat == 0 ? pA : pB) + h * 65536 + ts * 64;
#pragma unroll
    for (int c = 0; c < 2; ++c)
      gll16(base + goff[c], &lds[bb][mat][h][(c * 256 + tid) * 8]);
  };
  auto LDA = [&](int bb, int mt, int kk) {
    return *(const short8*)&lds[bb][0][wr][((((mt << 1) | kk) << 6) | lane) << 3];
  };
  auto LDB = [&](int bb, int nt, int kk) {
    return *(const short8*)&lds[bb][1][wc][((((nt << 1) | kk) << 6) | lane) << 3];
  };

  f32x4 acc[4][4] = {};
  short8 af[4][2], bfv[4][2];

  // prologue: tile0 all 4 halves, then h0(t1) A,B
  stage(0, 0, 0, 0); stage(0, 1, 0, 0); stage(0, 0, 1, 0); stage(0, 1, 1, 0);
  stage(1, 0, 0, 1); stage(1, 1, 0, 1);
  VMCNT4();
  BARRIER();

  auto tile = [&](int BUF, int t) {
    const int t1 = (t + 1 < 16) ? t + 1 : 15;
    const int t2 = (t + 2 < 16) ? t + 2 : 15;
    // ---- P0
#pragma unroll
    for (int m = 0; m < 2; ++m) { af[m][0] = LDA(BUF, m, 0); af[m][1] = LDA(BUF, m, 1); }
#pragma unroll
    for (int n = 0; n < 2; ++n) { bfv[n][0] = LDB(BUF, n, 0); bfv[n][1] = LDB(BUF, n, 1); }
    stage(BUF ^ 1, 0, 1, t1);
    FENCE(); BARRIER(); LGKM0();
    __builtin_amdgcn_s_setprio(1);
#pragma unroll
    for (int m = 0; m < 2; ++m)
#pragma unroll
      for (int n = 0; n < 2; ++n) {
        acc[m][n] = MFMA16(af[m][0], bfv[n][0], acc[m][n]);
        acc[m][n] = MFMA16(af[m][1], bfv[n][1], acc[m][n]);
      }
    __builtin_amdgcn_s_setprio(0);
    FENCE(); BARRIER();
    // ---- P1
#pragma unroll
    for (int m = 2; m < 4; ++m) { af[m][0] = LDA(BUF, m, 0); af[m][1] = LDA(BUF, m, 1); }
    stage(BUF ^ 1, 1, 1, t1);
    FENCE(); BARRIER(); LGKM0();
    __builtin_amdgcn_s_setprio(1);
#pragma unroll
    for (int m = 2; m < 4; ++m)
#pragma unroll
      for (int n = 0; n < 2; ++n) {
        acc[m][n] = MFMA16(af[m][0], bfv[n][0], acc[m][n]);
        acc[m][n] = MFMA16(af[m][1], bfv[n][1], acc[m][n]);
      }
    __builtin_amdgcn_s_setprio(0);
    FENCE(); BARRIER();
    // ---- P2
#pragma unroll
    for (int n = 2; n < 4; ++n) { bfv[n][0] = LDB(BUF, n, 0); bfv[n][1] = LDB(BUF, n, 1); }
    FENCE(); BARRIER(); LGKM0();
    __builtin_amdgcn_s_setprio(1);
#pragma unroll
    for (int m = 2; m < 4; ++m)
#pragma unroll
      for (int n = 2; n < 4; ++n) {
        acc[m][n] = MFMA16(af[m][0], bfv[n][0], acc[m][n]);
        acc[m][n] = MFMA16(af[m][1], bfv[n][1], acc[m][n]);
      }
    __builtin_amdgcn_s_setprio(0);
    FENCE(); BARRIER();
    // ---- P3: stage h0(t+2) into own buf (A read P0/P1, B-h read P0/P2 - done)
    stage(BUF, 0, 0, t2); stage(BUF, 1, 0, t2);
    FENCE();
    __builtin_amdgcn_s_setprio(1);
#pragma unroll
    for (int m = 0; m < 2; ++m)
#pragma unroll
      for (int n = 2; n < 4; ++n) {
        acc[m][n] = MFMA16(af[m][0], bfv[n][0], acc[m][n]);
        acc[m][n] = MFMA16(af[m][1], bfv[n][1], acc[m][n]);
      }
    __builtin_amdgcn_s_setprio(0);
    FENCE();
    VMCNT4();
    BARRIER();
  };

#pragma unroll
  for (int it = 0; it < 8; ++it) { tile(0, 2 * it); tile(1, 2 * it + 1); }
  VMCNT0();   // drain tail dummy stages before LDS goes out of scope

  // epilogue: C/D layout col = lane&15, row = (lane>>4)*4 + j
  if (MODE == 0) {
    const int p = col0 >> 10;                     // block-uniform
    u16* dst = (p == 0) ? qb : (p == 1) ? kbuf : vbuf;
    const int cc0 = (col0 & 1023) + (wc << 6) + (lane & 15);
#pragma unroll
    for (int m = 0; m < 4; ++m) {
      const int r0 = row0 + (wr << 6) + (m << 4) + ((lane >> 4) << 2);
#pragma unroll
      for (int j = 0; j < 4; ++j) {
        const int r = r0 + j;
        const float mv = (p == 0) ? 1.0f : ((mask[r] != 0) ? 1.0f : 0.0f);
#pragma unroll
        for (int n = 0; n < 4; ++n) {
          float v = acc[m][n][j];
          v = (p == 2) ? v * mv : gelu1p_f(v) * mv;
          dst[(size_t)r * 1024 + cc0 + (n << 4)] = f2bf(v);
        }
      }
    }
  } else {
    const int c0 = col0 + (wc << 6) + (lane & 15);
#pragma unroll
    for (int m = 0; m < 4; ++m) {
      const int r0 = row0 + (wr << 6) + (m << 4) + ((lane >> 4) << 2);
#pragma unroll
      for (int n = 0; n < 4; ++n)
#pragma unroll
        for (int j = 0; j < 4; ++j)
          outf[(size_t)(r0 + j) * 1024 + c0 + (n << 4)] = acc[m][n][j];
    }
  }
}

// ---------------------------------------------------------------------------
// Kernel 4: context partials via MFMA.  Grid (16 slices, 64 bh), 1 wave/block.
// Per slice of 512 t: Cp = K^T V (64x64) + z = sum K (via ones B-fragment).
// ---------------------------------------------------------------------------
__global__ __launch_bounds__(64)
void ctx_mfma(const u16* __restrict__ kbuf, const u16* __restrict__ vbuf,
              float* __restrict__ Cpart, float* __restrict__ zpart) {
  const int lane = threadIdx.x;
  const int bh = blockIdx.y, sl = blockIdx.x;     // sl 0..15
  const int b = bh >> 4, h = bh & 15;
  const size_t base = ((size_t)b * 8192 + (size_t)sl * 512) * 1024 + h * 64;
  const int colA = lane & 15;
  const int tj0 = (lane >> 4) << 3;

  short8 ones;
#pragma unroll
  for (int j = 0; j < 8; ++j) ones[j] = (short)0x3F80;  // bf16 1.0

  f32x4 acc[4][5] = {};                            // [di][ei], ei==4 -> z

  for (int c = 0; c < 16; ++c) {
    const size_t tbase = base + (size_t)(c * 32 + tj0) * 1024;
    short8 af[4], bv[4];
#pragma unroll
    for (int s = 0; s < 4; ++s) {
      const u16* pk = kbuf + tbase + s * 16 + colA;
      const u16* pv = vbuf + tbase + s * 16 + colA;
      short8 a, v;
#pragma unroll
      for (int j = 0; j < 8; ++j) { a[j] = (short)pk[j * 1024]; v[j] = (short)pv[j * 1024]; }
      af[s] = a; bv[s] = v;
    }
#pragma unroll
    for (int di = 0; di < 4; ++di) {
#pragma unroll
      for (int ei = 0; ei < 4; ++ei)
        acc[di][ei] = MFMA16(af[di], bv[ei], acc[di][ei]);
      acc[di][4] = MFMA16(af[di], ones, acc[di][4]);
    }
  }

  float* cp = Cpart + (size_t)(bh * 16 + sl) * 4096;
  const int el = lane & 15, rb = (lane >> 4) << 2;
#pragma unroll
  for (int di = 0; di < 4; ++di)
#pragma unroll
    for (int j = 0; j < 4; ++j) {
      const int d = di * 16 + rb + j;
#pragma unroll
      for (int ei = 0; ei < 4; ++ei)
        cp[d * 64 + ei * 16 + el] = acc[di][ei][j];
    }
  if (el == 0) {
    float* zp = zpart + (size_t)(bh * 16 + sl) * 64;
#pragma unroll
    for (int di = 0; di < 4; ++di)
#pragma unroll
      for (int j = 0; j < 4; ++j) zp[di * 16 + rb + j] = acc[di][4][j];
  }
}

// ---------------------------------------------------------------------------
// Kernel 5: reduce 16 slice-partials -> Cb bf16 [bh][64 d][80]  (col 64 = z)
// ---------------------------------------------------------------------------
__global__ void ctx_reduce(const float* __restrict__ Cpart, const float* __restrict__ zpart,
                           u16* __restrict__ Cb) {
  const int bh = blockIdx.x, tid = threadIdx.x;
  for (int idx = tid; idx < 5120; idx += 256) {
    const int d = idx / 80;
    const int e = idx - d * 80;
    float s = 0.f;
    if (e < 64) {
#pragma unroll
      for (int c = 0; c < 16; ++c) s += Cpart[(size_t)(bh * 16 + c) * 4096 + d * 64 + e];
    } else if (e == 64) {
#pragma unroll
      for (int c = 0; c < 16; ++c) s += zpart[(size_t)(bh * 16 + c) * 64 + d];
    }
    Cb[(size_t)bh * 5120 + idx] = f2bf(s);
  }
}

// ---------------------------------------------------------------------------
// Kernel 6: num/den via MFMA against Cb (z folded in as n-tile 4),
// ratio = num/(den+eps) -> bf16 (B,T,D layout, col = h*64+e)
// ---------------------------------------------------------------------------
__global__ __launch_bounds__(256)
void attn_out(const u16* __restrict__ qbuf, const u16* __restrict__ Cb,
              u16* __restrict__ ratio) {
  const int tid = threadIdx.x, lane = tid & 63, wave = tid >> 6;
  const int bh = blockIdx.y, b = bh >> 4, h = bh & 15;
  const int t0 = blockIdx.x * 256 + wave * 64;
  const size_t mbase = (size_t)b * 8192;
  const u16* cb = Cb + (size_t)bh * 5120;

  short8 bfrag[5][2];
#pragma unroll
  for (int nt = 0; nt < 5; ++nt)
#pragma unroll
    for (int kf = 0; kf < 2; ++kf) {
      short8 f;
#pragma unroll
      for (int j = 0; j < 8; ++j) {
        const int d = kf * 32 + ((lane >> 4) << 3) + j;
        f[j] = (short)cb[d * 80 + nt * 16 + (lane & 15)];
      }
      bfrag[nt][kf] = f;
    }

  f32x4 acc[4][5] = {};
#pragma unroll
  for (int mt = 0; mt < 4; ++mt) {
    const int tr = t0 + mt * 16 + (lane & 15);
    const u16* qrow = qbuf + (mbase + tr) * 1024 + h * 64 + ((lane >> 4) << 3);
    short8 a0 = *(const short8*)qrow;
    short8 a1 = *(const short8*)(qrow + 32);
#pragma unroll
    for (int nt = 0; nt < 5; ++nt) {
      acc[mt][nt] = MFMA16(a0, bfrag[nt][0], acc[mt][nt]);
      acc[mt][nt] = MFMA16(a1, bfrag[nt][1], acc[mt][nt]);
    }
  }

#pragma unroll
  for (int mt = 0; mt < 4; ++mt) {
#pragma unroll
    for (int j = 0; j < 4; ++j) {
      const float den = __shfl(acc[mt][4][j], lane & 48, 64);
      const float inv = 1.0f / (den + 1e-5f);
      const int tr = t0 + mt * 16 + ((lane >> 4) << 2) + j;
      u16* orow = ratio + (mbase + tr) * 1024 + h * 64;
#pragma unroll
      for (int nt = 0; nt < 4; ++nt)
        orow[nt * 16 + (lane & 15)] = f2bf(acc[mt][nt][j] * inv);
    }
  }
}

// ---------------------------------------------------------------------------
extern "C" void kernel_launch(void* const* d_in, const int* in_sizes, int n_in,
                              void* d_out, int out_size, void* d_ws, size_t ws_size,
                              hipStream_t stream) {
  (void)in_sizes; (void)n_in; (void)out_size; (void)ws_size;
  const float* x = (const float*)d_in[0];
  const int* mask = (const int*)d_in[1];   // bool promoted to int32 by harness
  const int* idx = (const int*)d_in[2];
  const float* wq = (const float*)d_in[3];
  const float* wk = (const float*)d_in[4];
  const float* wv = (const float*)d_in[5];
  const float* wo = (const float*)d_in[6];
  const float* lqd = (const float*)d_in[7];
  const float* lqu = (const float*)d_in[8];
  const float* lkd = (const float*)d_in[9];
  const float* lku = (const float*)d_in[10];
  const float* lvd = (const float*)d_in[11];
  const float* lvu = (const float*)d_in[12];
  const float* lod = (const float*)d_in[13];
  const float* lou = (const float*)d_in[14];
  float* out = (float*)d_out;

  char* ws = (char*)d_ws;
  u16* xb    = (u16*)ws;                      // 64 MB (x_bf16; later Cpart; later ratio)
  u16* wqkv  = (u16*)(ws + (64ll << 20));     // 6 MB
  u16* wo_b  = (u16*)(ws + (70ll << 20));     // 2 MB
  u16* qb    = (u16*)(ws + (72ll << 20));     // 64 MB
  u16* kb    = (u16*)(ws + (136ll << 20));    // 64 MB
  u16* vb    = (u16*)(ws + (200ll << 20));    // 64 MB
  float* Cpart = (float*)ws;                  // 16.8 MB, overlays dead xb
  float* zpart = (float*)(ws + (272ll << 20)); // 256 KB
  u16* Cb    = (u16*)(ws + (273ll << 20));    // 640 KB
  u16* ratio = xb;                            // attn_out output (after Cpart consumed)

  build_weff<<<dim3(4096), dim3(256), 0, stream>>>(wq, wk, wv, wo,
      lqd, lqu, lkd, lku, lvd, lvu, lod, lou, idx, wqkv, wo_b);
  xcast<<<dim3(16384), dim3(256), 0, stream>>>(x, xb);
  // QKV: M=32768, N=3072 -> grid 256x24 = 6144 (%8==0)
  gemm4w<0><<<dim3(6144), dim3(256), 0, stream>>>(xb, wqkv, qb, kb, vb, nullptr, mask, 24);
  ctx_mfma<<<dim3(16, 64), dim3(64), 0, stream>>>(kb, vb, Cpart, zpart);
  ctx_reduce<<<dim3(64), dim3(256), 0, stream>>>(Cpart, zpart, Cb);
  attn_out<<<dim3(32, 64), dim3(256), 0, stream>>>(qb, Cb, ratio);
  // out-proj: M=32768, N=1024 -> grid 256x8 = 2048 (%8==0)
  gemm4w<1><<<dim3(2048), dim3(256), 0, stream>>>(ratio, wo_b, nullptr, nullptr, nullptr, out, mask, 8);
}

// Round 7
// 487.871 us; speedup vs baseline: 1.4365x; 1.4365x over previous
//
#include <hip/hip_runtime.h>
#include <hip/hip_bf16.h>

typedef unsigned short u16;
typedef __attribute__((ext_vector_type(8))) short short8;
typedef __attribute__((ext_vector_type(4))) float f32x4;
typedef __attribute__((ext_vector_type(4))) unsigned short us4;
typedef __attribute__((ext_vector_type(8))) unsigned short us8;

__device__ __forceinline__ u16 f2bf(float f) {
  unsigned int u = __float_as_uint(f);
  u += 0x7fffu + ((u >> 16) & 1u);
  return (u16)(u >> 16);
}
__device__ __forceinline__ float bf2f(u16 h) {
  return __uint_as_float(((unsigned int)h) << 16);
}
// gelu1p(x) = 1 + x * Phi(x); Phi via A&S 7.1.26 erf approx (|eps|<=1.5e-7).
__device__ __forceinline__ float gelu1p_f(float x) {
  const float z  = x * 0.7071067811865475f;
  const float az = __builtin_fabsf(z);
  const float t  = __builtin_amdgcn_rcpf(__builtin_fmaf(0.3275911f, az, 1.0f));
  float pl = __builtin_fmaf(1.061405429f, t, -1.453152027f);
  pl = __builtin_fmaf(pl, t, 1.421413741f);
  pl = __builtin_fmaf(pl, t, -0.284496736f);
  pl = __builtin_fmaf(pl, t, 0.254829592f);
  pl = pl * t;
  const float e = __builtin_amdgcn_exp2f(-az * az * 1.4426950408889634f);
  float erfa = __builtin_fmaf(-pl, e, 1.0f);
  erfa = __builtin_copysignf(erfa, z);
  return __builtin_fmaf(x, 0.5f * (1.0f + erfa), 1.0f);
}
__device__ __forceinline__ void gll16(const void* g, void* l) {
  __builtin_amdgcn_global_load_lds(
      (const __attribute__((address_space(1))) unsigned int*)g,
      (__attribute__((address_space(3))) unsigned int*)l, 16, 0, 0);
}
#define FENCE() __builtin_amdgcn_sched_barrier(0)
#define BARRIER() __builtin_amdgcn_s_barrier()
#define LGKM0() do { asm volatile("s_waitcnt lgkmcnt(0)" ::: "memory"); FENCE(); } while (0)
#define VMCNT4() do { asm volatile("s_waitcnt vmcnt(4)" ::: "memory"); FENCE(); } while (0)
#define MFMA16(a, b, c) __builtin_amdgcn_mfma_f32_16x16x32_bf16(a, b, c, 0, 0, 0)

// ---------------------------------------------------------------------------
// Kernel 1: effective weights  W_eff = W + up[i] @ down[i]   (bf16 out)
// ---------------------------------------------------------------------------
__global__ __launch_bounds__(256)
void build_weff(const float* __restrict__ wq, const float* __restrict__ wk,
                const float* __restrict__ wv, const float* __restrict__ wo,
                const float* __restrict__ lqd, const float* __restrict__ lqu,
                const float* __restrict__ lkd, const float* __restrict__ lku,
                const float* __restrict__ lvd, const float* __restrict__ lvu,
                const float* __restrict__ lod, const float* __restrict__ lou,
                const int* __restrict__ idxp,
                u16* __restrict__ wqkv, u16* __restrict__ wout) {
  const int blk = blockIdx.x;        // 0..4095
  const int p = blk >> 10;
  const int n = blk & 1023;
  const int i = *idxp;
  const float* W  = (p == 0) ? wq  : (p == 1) ? wk  : (p == 2) ? wv  : wo;
  const float* Dn = ((p == 0) ? lqd : (p == 1) ? lkd : (p == 2) ? lvd : lod) + (size_t)i * 16 * 1024;
  const float* Up = ((p == 0) ? lqu : (p == 1) ? lku : (p == 2) ? lvu : lou) + (size_t)i * 1024 * 16;

  float up[16];
#pragma unroll
  for (int r = 0; r < 16; ++r) up[r] = Up[n * 16 + r];

  const int k0 = threadIdx.x << 2;
  f32x4 acc = *(const f32x4*)&W[(size_t)n * 1024 + k0];
#pragma unroll
  for (int r = 0; r < 16; ++r) {
    const f32x4 d = *(const f32x4*)&Dn[r * 1024 + k0];
#pragma unroll
    for (int j = 0; j < 4; ++j) acc[j] = __builtin_fmaf(up[r], d[j], acc[j]);
  }
  us4 o;
#pragma unroll
  for (int j = 0; j < 4; ++j) o[j] = f2bf(acc[j]);
  if (p < 3) *(us4*)&wqkv[(size_t)(p * 1024 + n) * 1024 + k0] = o;
  else       *(us4*)&wout[(size_t)n * 1024 + k0] = o;
}

// ---------------------------------------------------------------------------
// Kernel 2: x (f32) -> bf16
// ---------------------------------------------------------------------------
__global__ void xcast(const float* __restrict__ x, u16* __restrict__ xb) {
  const size_t i = ((size_t)blockIdx.x * 256 + threadIdx.x) * 8;
  f32x4 a = *(const f32x4*)(x + i);
  f32x4 b = *(const f32x4*)(x + i + 4);
  us8 o;
#pragma unroll
  for (int j = 0; j < 4; ++j) { o[j] = f2bf(a[j]); o[j + 4] = f2bf(b[j]); }
  *(us8*)(xb + i) = o;
}

// ---------------------------------------------------------------------------
// 256x256 8-phase bf16 GEMM (round-5 structure, REVERTED from 128^2 regression).
// C[M,N] = A[M,1024] * B[N,1024]^T.  BK=64, 8 waves (2Mx4N), per-wave 128x64.
// NEW vs round 5: G=4 grouped XCD swizzle -- within each XCD's contiguous
// chunk, hold bx for 4 consecutive by before advancing bx.  L2 working set
// becomes 4 A-panels + 1 B-block (~2.5 MB < 4 MB/XCD) so B panels get x4 L2
// reuse instead of being evicted every row sweep (B 6 MB > L2).
// Requires cpx % (4*nbx) == 0:  QKV 192%48==0, out-proj 64%16==0.
// ---------------------------------------------------------------------------
template <int MODE>
__global__ __launch_bounds__(512, 2)
void gemm8p(const u16* __restrict__ A, const u16* __restrict__ Bw,
            u16* __restrict__ qb, u16* __restrict__ kbuf, u16* __restrict__ vbuf,
            float* __restrict__ outf, const int* __restrict__ mask, int nbx) {
  const int nwg = gridDim.x;
  const int cpx = nwg >> 3;                       // tiles per XCD (nwg%8==0)
  const int xcd = blockIdx.x & 7;
  const int c   = blockIdx.x >> 3;                // 0..cpx-1 within chunk
  // grouped sweep: 4 rows per (g,bx) cell, bx advances after 4 rows
  const int g   = c / (nbx << 2);                 // row-group within chunk
  const int r   = c % (nbx << 2);
  const int bx  = r >> 2;
  const int byi = r & 3;
  const int rows_per_xcd = cpx / nbx;
  const int by  = xcd * rows_per_xcd + (g << 2) + byi;
  const int row0 = by << 8, col0 = bx << 8;
  const int tid = threadIdx.x, lane = tid & 63, w = tid >> 6;
  const int wr = w >> 2, wc = w & 3;

  __shared__ __align__(16) u16 lds[2][2][2][8192];  // 128 KiB

  // staging: per-thread global src (per-lane allowed), lane-linear LDS dest
  const int srow = (w << 4) + (lane & 15);        // row within a 128-row half
  const int scol = (lane >> 4) << 3;              // 8-col k-block within 32
  const u16* pA = A  + (size_t)(row0 + srow) * 1024 + scol;
  const u16* pB = Bw + (size_t)(col0 + srow) * 1024 + scol;

  auto stA = [&](int bb, int h, int ts) {
    const u16* s = pA + h * 131072 + ts * 64;
    u16* d = &lds[bb][0][h][((w << 7) + lane) << 3];
    gll16(s, d); gll16(s + 32, d + 512);
  };
  auto stB = [&](int bb, int h, int ts) {
    const u16* s = pB + h * 131072 + ts * 64;
    u16* d = &lds[bb][1][h][((w << 7) + lane) << 3];
    gll16(s, d); gll16(s + 32, d + 512);
  };
  auto LDA = [&](int bb, int m, int kk) {
    return *(const short8*)&lds[bb][0][wr][((((m << 1) | kk) << 6) | lane) << 3];
  };
  auto LDB = [&](int bb, int n, int kk) {
    const int nn = ((wc & 1) << 2) | n;
    return *(const short8*)&lds[bb][1][wc >> 1][((((nn << 1) | kk) << 6) | lane) << 3];
  };

  f32x4 acc[8][4] = {};
  short8 af[4][2], bfv[4][2];

  // prologue: tile0's 4 halves, then {Bh0,Ah0}(1) -> steady-state invariant
  stA(0, 0, 0); stB(0, 0, 0); stA(0, 1, 0); stB(0, 1, 0);
  stB(1, 0, 1); stA(1, 0, 1);
  VMCNT4();
  BARRIER();

  auto tile = [&](int BUF, int t) {
    const int t1 = (t + 1 < 16) ? t + 1 : 15;
    const int t2 = (t + 2 < 16) ? t + 2 : 15;
    // ---- P0: A m0-3 (8 reads) + B n0-1 (4 reads); stage Ah1(t+1)
#pragma unroll
    for (int m = 0; m < 4; ++m) { af[m][0] = LDA(BUF, m, 0); af[m][1] = LDA(BUF, m, 1); }
#pragma unroll
    for (int n = 0; n < 2; ++n) { bfv[n][0] = LDB(BUF, n, 0); bfv[n][1] = LDB(BUF, n, 1); }
    stA(BUF ^ 1, 1, t1);
    FENCE(); BARRIER(); LGKM0();
    __builtin_amdgcn_s_setprio(1);
#pragma unroll
    for (int m = 0; m < 4; ++m)
#pragma unroll
      for (int n = 0; n < 2; ++n) {
        acc[m][n] = MFMA16(af[m][0], bfv[n][0], acc[m][n]);
        acc[m][n] = MFMA16(af[m][1], bfv[n][1], acc[m][n]);
      }
    __builtin_amdgcn_s_setprio(0);
    FENCE(); BARRIER();
    // ---- P1: B n2-3 (4 reads); stage Bh1(t+1)
#pragma unroll
    for (int n = 2; n < 4; ++n) { bfv[n][0] = LDB(BUF, n, 0); bfv[n][1] = LDB(BUF, n, 1); }
    stB(BUF ^ 1, 1, t1);
    FENCE(); BARRIER(); LGKM0();
    __builtin_amdgcn_s_setprio(1);
#pragma unroll
    for (int m = 0; m < 4; ++m)
#pragma unroll
      for (int n = 2; n < 4; ++n) {
        acc[m][n] = MFMA16(af[m][0], bfv[n][0], acc[m][n]);
        acc[m][n] = MFMA16(af[m][1], bfv[n][1], acc[m][n]);
      }
    __builtin_amdgcn_s_setprio(0);
    FENCE(); BARRIER();
    // ---- P2: A m4-7 (8 reads); stage Bh0(t+2); reuse B n2-3
#pragma unroll
    for (int m = 0; m < 4; ++m) { af[m][0] = LDA(BUF, 4 + m, 0); af[m][1] = LDA(BUF, 4 + m, 1); }
    stB(BUF, 0, t2);
    FENCE(); BARRIER(); LGKM0();
    __builtin_amdgcn_s_setprio(1);
#pragma unroll
    for (int m = 0; m < 4; ++m)
#pragma unroll
      for (int n = 2; n < 4; ++n) {
        acc[4 + m][n] = MFMA16(af[m][0], bfv[n][0], acc[4 + m][n]);
        acc[4 + m][n] = MFMA16(af[m][1], bfv[n][1], acc[4 + m][n]);
      }
    __builtin_amdgcn_s_setprio(0);
    FENCE(); BARRIER();
    // ---- P3: no reads; stage Ah0(t+2); reuse A m4-7, B n0-1; vmcnt(4)
    stA(BUF, 0, t2);
    FENCE(); BARRIER();
    __builtin_amdgcn_s_setprio(1);
#pragma unroll
    for (int m = 0; m < 4; ++m)
#pragma unroll
      for (int n = 0; n < 2; ++n) {
        acc[4 + m][n] = MFMA16(af[m][0], bfv[n][0], acc[4 + m][n]);
        acc[4 + m][n] = MFMA16(af[m][1], bfv[n][1], acc[4 + m][n]);
      }
    __builtin_amdgcn_s_setprio(0);
    FENCE();
    VMCNT4();
    BARRIER();
  };

#pragma unroll
  for (int it = 0; it < 8; ++it) { tile(0, 2 * it); tile(1, 2 * it + 1); }

  // epilogue: C/D layout col = lane&15, row = (lane>>4)*4 + j
  if (MODE == 0) {
    const int cw = col0 + (wc << 6);
    const int p = cw >> 10;                       // wave-uniform
    u16* dst = (p == 0) ? qb : (p == 1) ? kbuf : vbuf;
    const int cc0 = (cw & 1023) + (lane & 15);
#pragma unroll
    for (int m = 0; m < 8; ++m) {
      const int r0 = row0 + (wr << 7) + (m << 4) + ((lane >> 4) << 2);
#pragma unroll
      for (int j = 0; j < 4; ++j) {
        const int r = r0 + j;
        const float mv = (p == 0) ? 1.0f : ((mask[r] != 0) ? 1.0f : 0.0f);
#pragma unroll
        for (int n = 0; n < 4; ++n) {
          float v = acc[m][n][j];
          v = (p == 2) ? v * mv : gelu1p_f(v) * mv;
          dst[(size_t)r * 1024 + cc0 + (n << 4)] = f2bf(v);
        }
      }
    }
  } else {
    const int c0 = col0 + (wc << 6) + (lane & 15);
#pragma unroll
    for (int m = 0; m < 8; ++m) {
      const int r0 = row0 + (wr << 7) + (m << 4) + ((lane >> 4) << 2);
#pragma unroll
      for (int n = 0; n < 4; ++n)
#pragma unroll
        for (int j = 0; j < 4; ++j)
          outf[(size_t)(r0 + j) * 1024 + c0 + (n << 4)] = acc[m][n][j];
    }
  }
}

// ---------------------------------------------------------------------------
// Kernel 4: context partials via MFMA.  Grid (16 slices, 64 bh), 1 wave/block.
// Per slice of 512 t: Cp = K^T V (64x64) + z = sum K (via ones B-fragment).
// ---------------------------------------------------------------------------
__global__ __launch_bounds__(64)
void ctx_mfma(const u16* __restrict__ kbuf, const u16* __restrict__ vbuf,
              float* __restrict__ Cpart, float* __restrict__ zpart) {
  const int lane = threadIdx.x;
  const int bh = blockIdx.y, sl = blockIdx.x;     // sl 0..15
  const int b = bh >> 4, h = bh & 15;
  const size_t base = ((size_t)b * 8192 + (size_t)sl * 512) * 1024 + h * 64;
  const int colA = lane & 15;
  const int tj0 = (lane >> 4) << 3;

  short8 ones;
#pragma unroll
  for (int j = 0; j < 8; ++j) ones[j] = (short)0x3F80;  // bf16 1.0

  f32x4 acc[4][5] = {};                            // [di][ei], ei==4 -> z

  for (int c = 0; c < 16; ++c) {
    const size_t tbase = base + (size_t)(c * 32 + tj0) * 1024;
    short8 af[4], bv[4];
#pragma unroll
    for (int s = 0; s < 4; ++s) {
      const u16* pk = kbuf + tbase + s * 16 + colA;
      const u16* pv = vbuf + tbase + s * 16 + colA;
      short8 a, v;
#pragma unroll
      for (int j = 0; j < 8; ++j) { a[j] = (short)pk[j * 1024]; v[j] = (short)pv[j * 1024]; }
      af[s] = a; bv[s] = v;
    }
#pragma unroll
    for (int di = 0; di < 4; ++di) {
#pragma unroll
      for (int ei = 0; ei < 4; ++ei)
        acc[di][ei] = MFMA16(af[di], bv[ei], acc[di][ei]);
      acc[di][4] = MFMA16(af[di], ones, acc[di][4]);
    }
  }

  float* cp = Cpart + (size_t)(bh * 16 + sl) * 4096;
  const int el = lane & 15, rb = (lane >> 4) << 2;
#pragma unroll
  for (int di = 0; di < 4; ++di)
#pragma unroll
    for (int j = 0; j < 4; ++j) {
      const int d = di * 16 + rb + j;
#pragma unroll
      for (int ei = 0; ei < 4; ++ei)
        cp[d * 64 + ei * 16 + el] = acc[di][ei][j];
    }
  if (el == 0) {
    float* zp = zpart + (size_t)(bh * 16 + sl) * 64;
#pragma unroll
    for (int di = 0; di < 4; ++di)
#pragma unroll
      for (int j = 0; j < 4; ++j) zp[di * 16 + rb + j] = acc[di][4][j];
  }
}

// ---------------------------------------------------------------------------
// Kernel 5: reduce 16 slice-partials -> Cb bf16 [bh][64 d][80]  (col 64 = z)
// ---------------------------------------------------------------------------
__global__ void ctx_reduce(const float* __restrict__ Cpart, const float* __restrict__ zpart,
                           u16* __restrict__ Cb) {
  const int bh = blockIdx.x, tid = threadIdx.x;
  for (int idx = tid; idx < 5120; idx += 256) {
    const int d = idx / 80;
    const int e = idx - d * 80;
    float s = 0.f;
    if (e < 64) {
#pragma unroll
      for (int c = 0; c < 16; ++c) s += Cpart[(size_t)(bh * 16 + c) * 4096 + d * 64 + e];
    } else if (e == 64) {
#pragma unroll
      for (int c = 0; c < 16; ++c) s += zpart[(size_t)(bh * 16 + c) * 64 + d];
    }
    Cb[(size_t)bh * 5120 + idx] = f2bf(s);
  }
}

// ---------------------------------------------------------------------------
// Kernel 6: num/den via MFMA against Cb (z folded in as n-tile 4),
// ratio = num/(den+eps) -> bf16 (B,T,D layout, col = h*64+e)
// ---------------------------------------------------------------------------
__global__ __launch_bounds__(256)
void attn_out(const u16* __restrict__ qbuf, const u16* __restrict__ Cb,
              u16* __restrict__ ratio) {
  const int tid = threadIdx.x, lane = tid & 63, wave = tid >> 6;
  const int bh = blockIdx.y, b = bh >> 4, h = bh & 15;
  const int t0 = blockIdx.x * 256 + wave * 64;
  const size_t mbase = (size_t)b * 8192;
  const u16* cb = Cb + (size_t)bh * 5120;

  short8 bfrag[5][2];
#pragma unroll
  for (int nt = 0; nt < 5; ++nt)
#pragma unroll
    for (int kf = 0; kf < 2; ++kf) {
      short8 f;
#pragma unroll
      for (int j = 0; j < 8; ++j) {
        const int d = kf * 32 + ((lane >> 4) << 3) + j;
        f[j] = (short)cb[d * 80 + nt * 16 + (lane & 15)];
      }
      bfrag[nt][kf] = f;
    }

  f32x4 acc[4][5] = {};
#pragma unroll
  for (int mt = 0; mt < 4; ++mt) {
    const int tr = t0 + mt * 16 + (lane & 15);
    const u16* qrow = qbuf + (mbase + tr) * 1024 + h * 64 + ((lane >> 4) << 3);
    short8 a0 = *(const short8*)qrow;
    short8 a1 = *(const short8*)(qrow + 32);
#pragma unroll
    for (int nt = 0; nt < 5; ++nt) {
      acc[mt][nt] = MFMA16(a0, bfrag[nt][0], acc[mt][nt]);
      acc[mt][nt] = MFMA16(a1, bfrag[nt][1], acc[mt][nt]);
    }
  }

#pragma unroll
  for (int mt = 0; mt < 4; ++mt) {
#pragma unroll
    for (int j = 0; j < 4; ++j) {
      const float den = __shfl(acc[mt][4][j], lane & 48, 64);
      const float inv = 1.0f / (den + 1e-5f);
      const int tr = t0 + mt * 16 + ((lane >> 4) << 2) + j;
      u16* orow = ratio + (mbase + tr) * 1024 + h * 64;
#pragma unroll
      for (int nt = 0; nt < 4; ++nt)
        orow[nt * 16 + (lane & 15)] = f2bf(acc[mt][nt][j] * inv);
    }
  }
}

// ---------------------------------------------------------------------------
extern "C" void kernel_launch(void* const* d_in, const int* in_sizes, int n_in,
                              void* d_out, int out_size, void* d_ws, size_t ws_size,
                              hipStream_t stream) {
  (void)in_sizes; (void)n_in; (void)out_size; (void)ws_size;
  const float* x = (const float*)d_in[0];
  const int* mask = (const int*)d_in[1];   // bool promoted to int32 by harness
  const int* idx = (const int*)d_in[2];
  const float* wq = (const float*)d_in[3];
  const float* wk = (const float*)d_in[4];
  const float* wv = (const float*)d_in[5];
  const float* wo = (const float*)d_in[6];
  const float* lqd = (const float*)d_in[7];
  const float* lqu = (const float*)d_in[8];
  const float* lkd = (const float*)d_in[9];
  const float* lku = (const float*)d_in[10];
  const float* lvd = (const float*)d_in[11];
  const float* lvu = (const float*)d_in[12];
  const float* lod = (const float*)d_in[13];
  const float* lou = (const float*)d_in[14];
  float* out = (float*)d_out;

  char* ws = (char*)d_ws;
  u16* xb    = (u16*)ws;                      // 64 MB (x_bf16; later Cpart; later ratio)
  u16* wqkv  = (u16*)(ws + (64ll << 20));     // 6 MB
  u16* wo_b  = (u16*)(ws + (70ll << 20));     // 2 MB
  u16* qb    = (u16*)(ws + (72ll << 20));     // 64 MB
  u16* kb    = (u16*)(ws + (136ll << 20));    // 64 MB
  u16* vb    = (u16*)(ws + (200ll << 20));    // 64 MB
  float* Cpart = (float*)ws;                  // 16.8 MB, overlays dead xb
  float* zpart = (float*)(ws + (272ll << 20)); // 256 KB
  u16* Cb    = (u16*)(ws + (273ll << 20));    // 640 KB
  u16* ratio = xb;                            // attn_out output (after Cpart consumed)

  build_weff<<<dim3(4096), dim3(256), 0, stream>>>(wq, wk, wv, wo,
      lqd, lqu, lkd, lku, lvd, lvu, lod, lou, idx, wqkv, wo_b);
  xcast<<<dim3(16384), dim3(256), 0, stream>>>(x, xb);
  // QKV: M=32768, N=3072 -> grid 128x12 = 1536 (%8==0, cpx=192, 192%48==0)
  gemm8p<0><<<dim3(1536), dim3(512), 0, stream>>>(xb, wqkv, qb, kb, vb, nullptr, mask, 12);
  ctx_mfma<<<dim3(16, 64), dim3(64), 0, stream>>>(kb, vb, Cpart, zpart);
  ctx_reduce<<<dim3(64), dim3(256), 0, stream>>>(Cpart, zpart, Cb);
  attn_out<<<dim3(32, 64), dim3(256), 0, stream>>>(qb, Cb, ratio);
  // out-proj: M=32768, N=1024 -> grid 128x4 = 512 (%8==0, cpx=64, 64%16==0)
  gemm8p<1><<<dim3(512), dim3(512), 0, stream>>>(ratio, wo_b, nullptr, nullptr, nullptr, out, mask, 4);
}